// Round 20
// baseline (1483.213 us; speedup 1.0000x reference)
//
#include <hip/hip_runtime.h>

#define N_PTS 8192
#define B_SZ 4
#define S_PTS 1024
#define K_SMP 32

// ======================= FPS =======================
// r19 audit: iter cost is ALL DS-pipe: 128 b128 point reads (~1536cy) +
// 96 ds_bpermute from __shfl butterfly (~576cy) + 64 b64 scan reads (~384cy).
// Fix: wave reduce via DPP (VALU pipe, zero DS): 6-step row_shr/row_bcast
// max on bestv, readlane(63); tie-resolve = DPP min over cand idx
// (cand = bestv==wavemax ? idx : 0xFFFFFFFF). Cross-wave scan packed as
// 4x ulonglong2. Per-lane strict-> ascending-j keeps lowest index (bit-exact);
// value-desc / index-asc ordering identical to r14-r19.
__device__ __forceinline__ float fps_dpp_max_f32(float v) {
    int a = __float_as_int(v);
#define FPS_DPP_STEP(ctrl) { \
    int b_ = __builtin_amdgcn_update_dpp(a, a, ctrl, 0xf, 0xf, false); \
    float f_ = fmaxf(__int_as_float(a), __int_as_float(b_)); \
    a = __float_as_int(f_); }
    FPS_DPP_STEP(0x111) FPS_DPP_STEP(0x112) FPS_DPP_STEP(0x114)
    FPS_DPP_STEP(0x118) FPS_DPP_STEP(0x142) FPS_DPP_STEP(0x143)
#undef FPS_DPP_STEP
    return __int_as_float(a);
}

__device__ __forceinline__ unsigned fps_dpp_min_u32(unsigned v) {
    int a = (int)v;
#define FPS_DPP_STEP(ctrl) { \
    int b_ = __builtin_amdgcn_update_dpp(a, a, ctrl, 0xf, 0xf, false); \
    unsigned m_ = ((unsigned)a < (unsigned)b_) ? (unsigned)a : (unsigned)b_; \
    a = (int)m_; }
    FPS_DPP_STEP(0x111) FPS_DPP_STEP(0x112) FPS_DPP_STEP(0x114)
    FPS_DPP_STEP(0x118) FPS_DPP_STEP(0x142) FPS_DPP_STEP(0x143)
#undef FPS_DPP_STEP
    return (unsigned)a;
}

#define FPS_ALL(M) M(0) M(1) M(2) M(3) M(4) M(5) M(6) M(7) \
                   M(8) M(9) M(10) M(11) M(12) M(13) M(14) M(15)

#define FPS_DECL(J) float dmin##J = 1e10f;

#define FPS_STEP(J) { \
    float4 p = lds4[t + J*512]; \
    float dx = __fsub_rn(p.x, cx); \
    float dy = __fsub_rn(p.y, cy); \
    float dz = __fsub_rn(p.z, cz); \
    float d  = __fadd_rn(__fadd_rn(__fmul_rn(dx, dx), __fmul_rn(dy, dy)), __fmul_rn(dz, dz)); \
    float dm = fminf(dmin##J, d); \
    dmin##J = dm; \
    if (dm > bestv) { bestv = dm; besti = t + J*512; } \
}

__global__ __launch_bounds__(512, 1) void fps_kernel(
    const float* __restrict__ xyz, int* __restrict__ fps_idx,
    float* __restrict__ out_newxyz)
{
    extern __shared__ float4 lds4[];
    __shared__ __align__(16) unsigned long long wkey[2][8];   // [parity][wave]

    const int b = blockIdx.x;
    const int t = threadIdx.x;
    const int wave = t >> 6;
    const int lane = t & 63;
    const float* xs = xyz + (size_t)b * 3 * N_PTS;
    const float* ys = xs + N_PTS;
    const float* zs = ys + N_PTS;

    // stage xyz into interleaved float4 LDS
    for (int i = t; i < N_PTS; i += 512) {
        float4 p; p.x = xs[i]; p.y = ys[i]; p.z = zs[i]; p.w = 0.f;
        lds4[i] = p;
    }
    __syncthreads();

    FPS_ALL(FPS_DECL)

    int far = 0;
    float4 c0 = lds4[0];
    float cx = c0.x, cy = c0.y, cz = c0.z;

    for (int s = 0; s < S_PTS; ++s) {
        if (t == 0) {
            fps_idx[b * S_PTS + s] = far;
            out_newxyz[((size_t)b * 3 + 0) * S_PTS + s] = cx;
            out_newxyz[((size_t)b * 3 + 1) * S_PTS + s] = cy;
            out_newxyz[((size_t)b * 3 + 2) * S_PTS + s] = cz;
        }
        float bestv = -1.0f; int besti = 0;
        FPS_ALL(FPS_STEP)

        // wave reduce on VALU (DPP): max value, then min index among ties
        float wm = fps_dpp_max_f32(bestv);
        float wavemax = __int_as_float(__builtin_amdgcn_readlane(__float_as_int(wm), 63));
        unsigned cand = (bestv == wavemax) ? (unsigned)besti : 0xFFFFFFFFu;
        unsigned im = fps_dpp_min_u32(cand);
        unsigned widx = (unsigned)__builtin_amdgcn_readlane((int)im, 63);

        const int par = s & 1;
        if (lane == 0) {
            wkey[par][wave] = ((unsigned long long)__float_as_uint(wavemax) << 32)
                            | (unsigned)(0xFFFFFFFFu - widx);
        }
        __syncthreads();
        // cross-wave scan: 8 keys as 4x ulonglong2
        unsigned long long bestk = 0ull;
        const ulonglong2* wk2 = (const ulonglong2*)&wkey[par][0];
#pragma unroll
        for (int q = 0; q < 4; ++q) {
            ulonglong2 kk = wk2[q];
            if (kk.x > bestk) bestk = kk.x;
            if (kk.y > bestk) bestk = kk.y;
        }
        far = (int)(0xFFFFFFFFu - (unsigned)bestk);
        float4 c = lds4[far];
        cx = c.x; cy = c.y; cz = c.z;
    }
}

// ======================= points transpose (B,D,N) -> (B,N,D) =======================
__global__ __launch_bounds__(256) void transpose_pts_kernel(
    const float* __restrict__ pts, float* __restrict__ ptsT)
{
    __shared__ float T[64][65];
    const int b  = blockIdx.y;
    const int n0 = blockIdx.x * 64;
    const int t  = threadIdx.x;
    const int c  = t & 63;
    const int r0 = (t >> 6) * 16;
#pragma unroll
    for (int rr = 0; rr < 16; ++rr) {
        int d = r0 + rr;
        T[d][c] = pts[((size_t)b * 64 + d) * N_PTS + n0 + c];
    }
    __syncthreads();
#pragma unroll
    for (int rr = 0; rr < 16; ++rr) {
        int n = r0 + rr;
        ptsT[((size_t)b * N_PTS + n0 + n) * 64 + c] = T[c][n];
    }
}

// ======================= ball query ======================= [verified pass r14-r19]
// Association (c): sqr = rn( rn(-2*dot + ps) + cs ), ascNoFMA dot.
__global__ __launch_bounds__(256) void ballq_kernel(
    const float* __restrict__ xyz, const int* __restrict__ fps_idx,
    int* __restrict__ gi)
{
    const int gw   = (blockIdx.x * 256 + threadIdx.x) >> 6;
    const int lane = threadIdx.x & 63;
    const int b = gw >> 10;
    const float* xs = xyz + (size_t)b * 3 * N_PTS;
    const float* ys = xs + N_PTS;
    const float* zs = ys + N_PTS;

    const int fi = fps_idx[gw];
    const float cx = xs[fi], cy = ys[fi], cz = zs[fi];
    const float cs = __fadd_rn(__fadd_rn(__fmul_rn(cx, cx), __fmul_rn(cy, cy)), __fmul_rn(cz, cz));

    int cnt = 0, myidx = 0, firstIdx = 0;
    for (int base = 0; base < N_PTS && cnt < K_SMP; base += 64) {
        int p = base + lane;
        float xx = xs[p], yy = ys[p], zz = zs[p];
        float dot = __fadd_rn(__fadd_rn(__fmul_rn(cx, xx), __fmul_rn(cy, yy)), __fmul_rn(cz, zz));
        float ps  = __fadd_rn(__fadd_rn(__fmul_rn(xx, xx), __fmul_rn(yy, yy)), __fmul_rn(zz, zz));
        float sqr = __fadd_rn(__fadd_rn(__fmul_rn(-2.0f, dot), ps), cs);   // (c)
        bool valid = !(sqr > 0.01f);
        unsigned long long mask = __ballot(valid);
        while (mask && cnt < K_SMP) {
            int bpos = __ffsll((long long)mask) - 1;
            mask &= mask - 1;
            if (cnt == lane) myidx = base + bpos;
            if (cnt == 0)    firstIdx = base + bpos;
            cnt++;
        }
    }
    if (lane < K_SMP) {
        if (lane >= cnt) myidx = firstIdx;
        gi[(size_t)gw * K_SMP + lane] = myidx;
    }
}

// ======================= K1: layer-0 stats only (no y store) =======================
__global__ __launch_bounds__(256) void conv0_stats_kernel(
    const float* __restrict__ xyz, const float* __restrict__ ptsT,
    const int* __restrict__ fps_idx, const int* __restrict__ gi,
    const float* __restrict__ W0, const float* __restrict__ bias0,
    float* __restrict__ stats0)
{
    __shared__ float A[128 * 68];
    __shared__ float Wt[68 * 64];
    __shared__ float cent[4][3];
    __shared__ float bsh[64];
    __shared__ float sred[128];

    const int t = threadIdx.x;
    const size_t pos0 = (size_t)blockIdx.x * 128;
    const int b  = (int)(pos0 >> 15);
    const int s0 = (int)((pos0 >> 5) & (S_PTS - 1));
    const float* xs = xyz + (size_t)b * 3 * N_PTS;
    const float* ys = xs + N_PTS;
    const float* zs = ys + N_PTS;

    if (t < 4) {
        int fi = fps_idx[b * S_PTS + s0 + t];
        cent[t][0] = xs[fi]; cent[t][1] = ys[fi]; cent[t][2] = zs[fi];
    }
    if (t >= 128 && t < 192) bsh[t - 128] = bias0[t - 128];
    if (t >= 192) { sred[t - 192] = 0.f; sred[t - 128] = 0.f; }
    for (int i = t; i < 68 * 64; i += 256) {
        int c = i >> 6, o = i & 63;
        float v = 0.f;
        if (c < 64) v = W0[o * 67 + 3 + c];
        else if (c < 67) v = W0[o * 67 + (c - 64)];
        Wt[i] = v;
    }
    for (int i = t; i < 128 * 16; i += 256) {
        int pos = i >> 4, j = i & 15;
        float4 v = *(const float4*)(ptsT + ((size_t)b * N_PTS + gi[pos0 + pos]) * 64 + j * 4);
        *(float4*)(A + pos * 68 + j * 4) = v;
    }
    __syncthreads();
    if (t < 128) {
        int g = gi[pos0 + t]; int ci = t >> 5;
        A[t * 68 + 64] = __fsub_rn(xs[g], cent[ci][0]);
        A[t * 68 + 65] = __fsub_rn(ys[g], cent[ci][1]);
        A[t * 68 + 66] = __fsub_rn(zs[g], cent[ci][2]);
        A[t * 68 + 67] = 0.f;
    }
    __syncthreads();

    const int og = t & 15;
    const int pg = t >> 4;
    float acc[8][4];
#pragma unroll
    for (int r = 0; r < 8; ++r)
#pragma unroll
        for (int c = 0; c < 4; ++c) acc[r][c] = 0.f;

    for (int j = 0; j < 17; ++j) {
        float w[4][4];
#pragma unroll
        for (int cc = 0; cc < 4; ++cc) {
            float4 v = *(const float4*)(Wt + (j * 4 + cc) * 64 + og * 4);
            w[cc][0] = v.x; w[cc][1] = v.y; w[cc][2] = v.z; w[cc][3] = v.w;
        }
#pragma unroll
        for (int r = 0; r < 8; ++r) {
            float4 v = *(const float4*)(A + (pg + r * 16) * 68 + j * 4);
#pragma unroll
            for (int co = 0; co < 4; ++co) {
                float s = acc[r][co];
                s = fmaf(v.x, w[0][co], s);
                s = fmaf(v.y, w[1][co], s);
                s = fmaf(v.z, w[2][co], s);
                s = fmaf(v.w, w[3][co], s);
                acc[r][co] = s;
            }
        }
    }

    float sum[4] = {0,0,0,0}, ssq[4] = {0,0,0,0};
#pragma unroll
    for (int r = 0; r < 8; ++r)
#pragma unroll
        for (int c = 0; c < 4; ++c) {
            float yv = acc[r][c] + bsh[og * 4 + c];
            sum[c] += yv; ssq[c] = fmaf(yv, yv, ssq[c]);
        }
#pragma unroll
    for (int c = 0; c < 4; ++c) {
        atomicAdd(&sred[og * 4 + c], sum[c]);
        atomicAdd(&sred[64 + og * 4 + c], ssq[c]);
    }
    __syncthreads();
    if (t < 128) atomicAdd(&stats0[t], sred[t]);
}

// ======================= K2: recompute mm0 -> BN0 -> mm1, layer-1 stats =======================
__global__ __launch_bounds__(256) void conv1_stats_kernel(
    const float* __restrict__ xyz, const float* __restrict__ ptsT,
    const int* __restrict__ fps_idx, const int* __restrict__ gi,
    const float* __restrict__ W0, const float* __restrict__ bias0,
    const float* __restrict__ W1, const float* __restrict__ bias1,
    const float* __restrict__ scl0, const float* __restrict__ sh0,
    float* __restrict__ stats1)
{
    __shared__ float A[64 * 68];
    __shared__ float W0t[68 * 64];
    __shared__ float W1t[64 * 64];
    __shared__ float cent[2][3];
    __shared__ float b0sh[64], b1sh[64], s0sh[64], h0sh[64];
    __shared__ float sred[128];

    const int t = threadIdx.x;
    const size_t pos0 = (size_t)blockIdx.x * 64;
    const int b  = (int)(pos0 >> 15);
    const int s0 = (int)((pos0 >> 5) & (S_PTS - 1));
    const float* xs = xyz + (size_t)b * 3 * N_PTS;
    const float* ys = xs + N_PTS;
    const float* zs = ys + N_PTS;

    if (t < 2) {
        int fi = fps_idx[b * S_PTS + s0 + t];
        cent[t][0] = xs[fi]; cent[t][1] = ys[fi]; cent[t][2] = zs[fi];
    }
    if (t >= 64 && t < 128) { b0sh[t-64] = bias0[t-64]; b1sh[t-64] = bias1[t-64]; }
    if (t >= 128 && t < 192) { s0sh[t-128] = scl0[t-128]; h0sh[t-128] = sh0[t-128]; }
    if (t >= 192) { sred[t-192] = 0.f; sred[t-128] = 0.f; }
    for (int i = t; i < 68 * 64; i += 256) {
        int c = i >> 6, o = i & 63;
        float v = 0.f;
        if (c < 64) v = W0[o * 67 + 3 + c];
        else if (c < 67) v = W0[o * 67 + (c - 64)];
        W0t[i] = v;
    }
    for (int i = t; i < 64 * 64; i += 256) { int c = i >> 6, o = i & 63; W1t[i] = W1[o * 64 + c]; }
    for (int i = t; i < 64 * 16; i += 256) {
        int pos = i >> 4, j = i & 15;
        float4 v = *(const float4*)(ptsT + ((size_t)b * N_PTS + gi[pos0 + pos]) * 64 + j * 4);
        *(float4*)(A + pos * 68 + j * 4) = v;
    }
    __syncthreads();
    if (t < 64) {
        int g = gi[pos0 + t]; int ci = t >> 5;
        A[t * 68 + 64] = __fsub_rn(xs[g], cent[ci][0]);
        A[t * 68 + 65] = __fsub_rn(ys[g], cent[ci][1]);
        A[t * 68 + 66] = __fsub_rn(zs[g], cent[ci][2]);
        A[t * 68 + 67] = 0.f;
    }
    __syncthreads();

    const int og = t & 15;
    const int pg = t >> 4;
    float acc[4][4];
#pragma unroll
    for (int r = 0; r < 4; ++r)
#pragma unroll
        for (int c = 0; c < 4; ++c) acc[r][c] = 0.f;

    for (int j = 0; j < 17; ++j) {
        float w[4][4];
#pragma unroll
        for (int cc = 0; cc < 4; ++cc) {
            float4 v = *(const float4*)(W0t + (j * 4 + cc) * 64 + og * 4);
            w[cc][0] = v.x; w[cc][1] = v.y; w[cc][2] = v.z; w[cc][3] = v.w;
        }
#pragma unroll
        for (int r = 0; r < 4; ++r) {
            float4 v = *(const float4*)(A + (pg + r * 16) * 68 + j * 4);
#pragma unroll
            for (int co = 0; co < 4; ++co) {
                float s = acc[r][co];
                s = fmaf(v.x, w[0][co], s);
                s = fmaf(v.y, w[1][co], s);
                s = fmaf(v.z, w[2][co], s);
                s = fmaf(v.w, w[3][co], s);
                acc[r][co] = s;
            }
        }
    }
    __syncthreads();
#pragma unroll
    for (int r = 0; r < 4; ++r) {
        float4 z;
        z.x = fmaxf(fmaf(acc[r][0] + b0sh[og*4+0], s0sh[og*4+0], h0sh[og*4+0]), 0.f);
        z.y = fmaxf(fmaf(acc[r][1] + b0sh[og*4+1], s0sh[og*4+1], h0sh[og*4+1]), 0.f);
        z.z = fmaxf(fmaf(acc[r][2] + b0sh[og*4+2], s0sh[og*4+2], h0sh[og*4+2]), 0.f);
        z.w = fmaxf(fmaf(acc[r][3] + b0sh[og*4+3], s0sh[og*4+3], h0sh[og*4+3]), 0.f);
        *(float4*)(A + (pg + r * 16) * 68 + og * 4) = z;
    }
    __syncthreads();
    float acc1[4][4];
#pragma unroll
    for (int r = 0; r < 4; ++r)
#pragma unroll
        for (int c = 0; c < 4; ++c) acc1[r][c] = 0.f;
    for (int j = 0; j < 16; ++j) {
        float w[4][4];
#pragma unroll
        for (int cc = 0; cc < 4; ++cc) {
            float4 v = *(const float4*)(W1t + (j * 4 + cc) * 64 + og * 4);
            w[cc][0] = v.x; w[cc][1] = v.y; w[cc][2] = v.z; w[cc][3] = v.w;
        }
#pragma unroll
        for (int r = 0; r < 4; ++r) {
            float4 v = *(const float4*)(A + (pg + r * 16) * 68 + j * 4);
#pragma unroll
            for (int co = 0; co < 4; ++co) {
                float s = acc1[r][co];
                s = fmaf(v.x, w[0][co], s);
                s = fmaf(v.y, w[1][co], s);
                s = fmaf(v.z, w[2][co], s);
                s = fmaf(v.w, w[3][co], s);
                acc1[r][co] = s;
            }
        }
    }
    float sum[4] = {0,0,0,0}, ssq[4] = {0,0,0,0};
#pragma unroll
    for (int r = 0; r < 4; ++r)
#pragma unroll
        for (int c = 0; c < 4; ++c) {
            float yv = acc1[r][c] + b1sh[og * 4 + c];
            sum[c] += yv; ssq[c] = fmaf(yv, yv, ssq[c]);
        }
#pragma unroll
    for (int c = 0; c < 4; ++c) {
        atomicAdd(&sred[og * 4 + c], sum[c]);
        atomicAdd(&sred[64 + og * 4 + c], ssq[c]);
    }
    __syncthreads();
    if (t < 128) atomicAdd(&stats1[t], sred[t]);
}

// ======================= K3: full chain -> layer-2 stats + K-max =======================
__global__ __launch_bounds__(256) void conv2_final_kernel(
    const float* __restrict__ xyz, const float* __restrict__ ptsT,
    const int* __restrict__ fps_idx, const int* __restrict__ gi,
    const float* __restrict__ W0, const float* __restrict__ bias0,
    const float* __restrict__ W1, const float* __restrict__ bias1,
    const float* __restrict__ W2, const float* __restrict__ bias2,
    const float* __restrict__ scl0, const float* __restrict__ sh0,
    const float* __restrict__ scl1, const float* __restrict__ sh1,
    float* __restrict__ mout, float* __restrict__ stats2)
{
    __shared__ float A[64 * 68];
    __shared__ float Wb[8192];
    __shared__ float cent[2][3];
    __shared__ float b0sh[64], b1sh[64], b2sh[128];
    __shared__ float s0sh[64], h0sh[64], s1sh[64], h1sh[64];
    __shared__ float sred[256];
    __shared__ float maxbuf[2][8][128];

    const int t = threadIdx.x;
    const size_t pos0 = (size_t)blockIdx.x * 64;
    const int b  = (int)(pos0 >> 15);
    const int s0 = (int)((pos0 >> 5) & (S_PTS - 1));
    const float* xs = xyz + (size_t)b * 3 * N_PTS;
    const float* ys = xs + N_PTS;
    const float* zs = ys + N_PTS;

    if (t < 2) {
        int fi = fps_idx[b * S_PTS + s0 + t];
        cent[t][0] = xs[fi]; cent[t][1] = ys[fi]; cent[t][2] = zs[fi];
    }
    if (t < 64) { s0sh[t] = scl0[t]; h0sh[t] = sh0[t]; }
    else if (t < 128) { s1sh[t-64] = scl1[t-64]; h1sh[t-64] = sh1[t-64]; }
    else if (t < 192) { b0sh[t-128] = bias0[t-128]; b1sh[t-128] = bias1[t-128]; }
    else { int q = (t - 192) * 4; sred[q]=0.f; sred[q+1]=0.f; sred[q+2]=0.f; sred[q+3]=0.f; }
    if (t < 128) b2sh[t] = bias2[t];
    for (int i = t; i < 68 * 64; i += 256) {
        int c = i >> 6, o = i & 63;
        float v = 0.f;
        if (c < 64) v = W0[o * 67 + 3 + c];
        else if (c < 67) v = W0[o * 67 + (c - 64)];
        Wb[i] = v;
    }
    for (int i = t; i < 64 * 16; i += 256) {
        int pos = i >> 4, j = i & 15;
        float4 v = *(const float4*)(ptsT + ((size_t)b * N_PTS + gi[pos0 + pos]) * 64 + j * 4);
        *(float4*)(A + pos * 68 + j * 4) = v;
    }
    __syncthreads();
    if (t < 64) {
        int g = gi[pos0 + t]; int ci = t >> 5;
        A[t * 68 + 64] = __fsub_rn(xs[g], cent[ci][0]);
        A[t * 68 + 65] = __fsub_rn(ys[g], cent[ci][1]);
        A[t * 68 + 66] = __fsub_rn(zs[g], cent[ci][2]);
        A[t * 68 + 67] = 0.f;
    }
    __syncthreads();

    const int og = t & 15;
    const int pg = t >> 4;
    float acc[4][4];
#pragma unroll
    for (int r = 0; r < 4; ++r)
#pragma unroll
        for (int c = 0; c < 4; ++c) acc[r][c] = 0.f;
    for (int j = 0; j < 17; ++j) {
        float w[4][4];
#pragma unroll
        for (int cc = 0; cc < 4; ++cc) {
            float4 v = *(const float4*)(Wb + (j * 4 + cc) * 64 + og * 4);
            w[cc][0] = v.x; w[cc][1] = v.y; w[cc][2] = v.z; w[cc][3] = v.w;
        }
#pragma unroll
        for (int r = 0; r < 4; ++r) {
            float4 v = *(const float4*)(A + (pg + r * 16) * 68 + j * 4);
#pragma unroll
            for (int co = 0; co < 4; ++co) {
                float s = acc[r][co];
                s = fmaf(v.x, w[0][co], s);
                s = fmaf(v.y, w[1][co], s);
                s = fmaf(v.z, w[2][co], s);
                s = fmaf(v.w, w[3][co], s);
                acc[r][co] = s;
            }
        }
    }
    __syncthreads();
#pragma unroll
    for (int r = 0; r < 4; ++r) {
        float4 z;
        z.x = fmaxf(fmaf(acc[r][0] + b0sh[og*4+0], s0sh[og*4+0], h0sh[og*4+0]), 0.f);
        z.y = fmaxf(fmaf(acc[r][1] + b0sh[og*4+1], s0sh[og*4+1], h0sh[og*4+1]), 0.f);
        z.z = fmaxf(fmaf(acc[r][2] + b0sh[og*4+2], s0sh[og*4+2], h0sh[og*4+2]), 0.f);
        z.w = fmaxf(fmaf(acc[r][3] + b0sh[og*4+3], s0sh[og*4+3], h0sh[og*4+3]), 0.f);
        *(float4*)(A + (pg + r * 16) * 68 + og * 4) = z;
    }
    for (int i = t; i < 64 * 64; i += 256) { int c = i >> 6, o = i & 63; Wb[i] = W1[o * 64 + c]; }
    __syncthreads();
    float acc1[4][4];
#pragma unroll
    for (int r = 0; r < 4; ++r)
#pragma unroll
        for (int c = 0; c < 4; ++c) acc1[r][c] = 0.f;
    for (int j = 0; j < 16; ++j) {
        float w[4][4];
#pragma unroll
        for (int cc = 0; cc < 4; ++cc) {
            float4 v = *(const float4*)(Wb + (j * 4 + cc) * 64 + og * 4);
            w[cc][0] = v.x; w[cc][1] = v.y; w[cc][2] = v.z; w[cc][3] = v.w;
        }
#pragma unroll
        for (int r = 0; r < 4; ++r) {
            float4 v = *(const float4*)(A + (pg + r * 16) * 68 + j * 4);
#pragma unroll
            for (int co = 0; co < 4; ++co) {
                float s = acc1[r][co];
                s = fmaf(v.x, w[0][co], s);
                s = fmaf(v.y, w[1][co], s);
                s = fmaf(v.z, w[2][co], s);
                s = fmaf(v.w, w[3][co], s);
                acc1[r][co] = s;
            }
        }
    }
    __syncthreads();
#pragma unroll
    for (int r = 0; r < 4; ++r) {
        float4 z;
        z.x = fmaxf(fmaf(acc1[r][0] + b1sh[og*4+0], s1sh[og*4+0], h1sh[og*4+0]), 0.f);
        z.y = fmaxf(fmaf(acc1[r][1] + b1sh[og*4+1], s1sh[og*4+1], h1sh[og*4+1]), 0.f);
        z.z = fmaxf(fmaf(acc1[r][2] + b1sh[og*4+2], s1sh[og*4+2], h1sh[og*4+2]), 0.f);
        z.w = fmaxf(fmaf(acc1[r][3] + b1sh[og*4+3], s1sh[og*4+3], h1sh[og*4+3]), 0.f);
        *(float4*)(A + (pg + r * 16) * 68 + og * 4) = z;
    }
    for (int i = t; i < 64 * 128; i += 256) { int c = i >> 7, o = i & 127; Wb[i] = W2[o * 64 + c]; }
    __syncthreads();
    const int og2 = t & 31;
    const int pg2 = t >> 5;
    float acc2[8][4];
#pragma unroll
    for (int r = 0; r < 8; ++r)
#pragma unroll
        for (int c = 0; c < 4; ++c) acc2[r][c] = 0.f;
    for (int j = 0; j < 16; ++j) {
        float w[4][4];
#pragma unroll
        for (int cc = 0; cc < 4; ++cc) {
            float4 v = *(const float4*)(Wb + (j * 4 + cc) * 128 + og2 * 4);
            w[cc][0] = v.x; w[cc][1] = v.y; w[cc][2] = v.z; w[cc][3] = v.w;
        }
#pragma unroll
        for (int r = 0; r < 8; ++r) {
            float4 v = *(const float4*)(A + (pg2 + r * 8) * 68 + j * 4);
#pragma unroll
            for (int co = 0; co < 4; ++co) {
                float s = acc2[r][co];
                s = fmaf(v.x, w[0][co], s);
                s = fmaf(v.y, w[1][co], s);
                s = fmaf(v.z, w[2][co], s);
                s = fmaf(v.w, w[3][co], s);
                acc2[r][co] = s;
            }
        }
    }
    float sum[4] = {0,0,0,0}, ssq[4] = {0,0,0,0};
    float mx0[4], mx1[4];
#pragma unroll
    for (int c = 0; c < 4; ++c) { mx0[c] = -3.402823466e38f; mx1[c] = -3.402823466e38f; }
#pragma unroll
    for (int r = 0; r < 8; ++r)
#pragma unroll
        for (int c = 0; c < 4; ++c) {
            float yv = acc2[r][c] + b2sh[og2 * 4 + c];
            sum[c] += yv; ssq[c] = fmaf(yv, yv, ssq[c]);
            if (r < 4) mx0[c] = fmaxf(mx0[c], yv);
            else       mx1[c] = fmaxf(mx1[c], yv);
        }
#pragma unroll
    for (int c = 0; c < 4; ++c) {
        atomicAdd(&sred[og2 * 4 + c], sum[c]);
        atomicAdd(&sred[128 + og2 * 4 + c], ssq[c]);
        maxbuf[0][pg2][og2 * 4 + c] = mx0[c];
        maxbuf[1][pg2][og2 * 4 + c] = mx1[c];
    }
    __syncthreads();
    {
        int cent2 = t >> 7, o = t & 127;
        float v = maxbuf[cent2][0][o];
#pragma unroll
        for (int q = 1; q < 8; ++q) v = fmaxf(v, maxbuf[cent2][q][o]);
        mout[(size_t)(blockIdx.x * 2 + cent2) * 128 + o] = v;
        atomicAdd(&stats2[t], sred[t]);
    }
}

// ======================= BN finalize =======================
__global__ void finalize_kernel(const float* __restrict__ stats, const float* __restrict__ g,
                                const float* __restrict__ beta, float* __restrict__ scl,
                                float* __restrict__ sh, int C)
{
    int c = threadIdx.x;
    if (c >= C) return;
    const float inv = 1.0f / 131072.0f;
    float mean = stats[c] * inv;
    float var  = stats[C + c] * inv - mean * mean;
    var = fmaxf(var, 0.f);
    float s = g[c] / sqrtf(var + 1e-5f);
    scl[c] = s;
    sh[c] = beta[c] - mean * s;
}

// ======================= writeout =======================
__global__ __launch_bounds__(256) void writeout_kernel(
    const float* __restrict__ m, const float* __restrict__ scl,
    const float* __restrict__ sh, float* __restrict__ out)
{
    int idx = blockIdx.x * 256 + threadIdx.x;
    int s = idx & 1023;
    int o = (idx >> 10) & 127;
    int b = idx >> 17;
    float v = m[(size_t)((b << 10) + s) * 128 + o];
    v = fmaxf(fmaf(v, scl[o], sh[o]), 0.f);
    out[idx] = v;
}

// ======================= launch =======================
extern "C" void kernel_launch(void* const* d_in, const int* in_sizes, int n_in,
                              void* d_out, int out_size, void* d_ws, size_t ws_size,
                              hipStream_t stream)
{
    const float* xyz = (const float*)d_in[0];
    const float* pts = (const float*)d_in[1];
    const float* W0  = (const float*)d_in[2];
    const float* b0  = (const float*)d_in[3];
    const float* g0  = (const float*)d_in[4];
    const float* be0 = (const float*)d_in[5];
    const float* W1  = (const float*)d_in[6];
    const float* b1  = (const float*)d_in[7];
    const float* g1  = (const float*)d_in[8];
    const float* be1 = (const float*)d_in[9];
    const float* W2  = (const float*)d_in[10];
    const float* b2  = (const float*)d_in[11];
    const float* g2  = (const float*)d_in[12];
    const float* be2 = (const float*)d_in[13];
    float* out = (float*)d_out;

    char* ws = (char*)d_ws;
    int*   fps_idx = (int*)(ws + 0);              // 16 KB
    int*   gi      = (int*)(ws + 16384);          // 512 KB -> ends 540672
    float* stats   = (float*)(ws + 540672);       // 512 f
    float* ss      = (float*)(ws + 542720);       // 512 f
    float* m       = (float*)(ws + 544768);       // 2 MB
    float* ptsT    = (float*)(ws + 2641920);      // 8 MB -> ends ~10.5 MB
    float *scl0 = ss, *sh0 = ss + 64, *scl1 = ss + 128, *sh1 = ss + 192,
          *scl2 = ss + 256, *sh2 = ss + 384;

    hipMemsetAsync(stats, 0, 2048, stream);

    hipFuncSetAttribute((const void*)fps_kernel,
                        hipFuncAttributeMaxDynamicSharedMemorySize, N_PTS * 16);
    hipLaunchKernelGGL(fps_kernel, dim3(4), dim3(512), N_PTS * 16, stream,
                       xyz, fps_idx, out);
    hipLaunchKernelGGL(transpose_pts_kernel, dim3(128, 4), dim3(256), 0, stream, pts, ptsT);
    hipLaunchKernelGGL(ballq_kernel, dim3(1024), dim3(256), 0, stream, xyz, fps_idx, gi);
    hipLaunchKernelGGL(conv0_stats_kernel, dim3(1024), dim3(256), 0, stream,
                       xyz, ptsT, fps_idx, gi, W0, b0, stats);
    hipLaunchKernelGGL(finalize_kernel, dim3(1), dim3(64), 0, stream, stats, g0, be0, scl0, sh0, 64);
    hipLaunchKernelGGL(conv1_stats_kernel, dim3(2048), dim3(256), 0, stream,
                       xyz, ptsT, fps_idx, gi, W0, b0, W1, b1, scl0, sh0, stats + 128);
    hipLaunchKernelGGL(finalize_kernel, dim3(1), dim3(64), 0, stream, stats + 128, g1, be1, scl1, sh1, 64);
    hipLaunchKernelGGL(conv2_final_kernel, dim3(2048), dim3(256), 0, stream,
                       xyz, ptsT, fps_idx, gi, W0, b0, W1, b1, W2, b2,
                       scl0, sh0, scl1, sh1, m, stats + 256);
    hipLaunchKernelGGL(finalize_kernel, dim3(1), dim3(128), 0, stream, stats + 256, g2, be2, scl2, sh2, 128);
    hipLaunchKernelGGL(writeout_kernel, dim3(2048), dim3(256), 0, stream, m, scl2, sh2, out + 12288);
}